// Round 1
// baseline (311.599 us; speedup 1.0000x reference)
//
#include <hip/hip_runtime.h>

#define Bn 64
#define Tn 512
#define Hn 768
#define Ln 21
#define EM_ELEMS (Bn*Tn*Ln)

// ---------------- emissions = hidden @ W + b ----------------
// thread-per-row, W staged in LDS (64.5 KB), float4 loads of hidden.
__global__ __launch_bounds__(128) void emis_kernel(
    const float* __restrict__ hidden, const float* __restrict__ W,
    const float* __restrict__ bias, float* __restrict__ em)
{
    __shared__ float Wl[Hn*Ln];
    for (int i = threadIdx.x; i < Hn*Ln; i += 128) Wl[i] = W[i];
    __syncthreads();
    int row = blockIdx.x*128 + threadIdx.x;           // 0 .. B*T-1
    const float4* h4 = (const float4*)(hidden + (size_t)row*Hn);
    float acc[Ln];
    #pragma unroll
    for (int j=0;j<Ln;++j) acc[j]=bias[j];
    #pragma unroll 2
    for (int k4=0;k4<Hn/4;++k4){
        float4 h = h4[k4];
        const float* hv = &h.x;
        #pragma unroll
        for (int c=0;c<4;++c){
            float x = hv[c];
            const float* wr = &Wl[(k4*4+c)*Ln];
            #pragma unroll
            for (int j=0;j<Ln;++j) acc[j] = fmaf(x, wr[j], acc[j]);
        }
    }
    float* o = em + (size_t)row*Ln;
    #pragma unroll
    for (int j=0;j<Ln;++j) o[j]=acc[j];
}

// ---------------- CRF scan: blocks 0..63 = NLL(per-batch), 64..127 = Viterbi ----------------
__global__ __launch_bounds__(64) void crf_kernel(
    const float* __restrict__ em_g, const int* __restrict__ labels,
    const int* __restrict__ amask, const float* __restrict__ st,
    const float* __restrict__ et, const float* __restrict__ trans,
    float* __restrict__ ws_out, float* __restrict__ logits)
{
    const int b    = blockIdx.x & (Bn-1);
    const int mode = blockIdx.x >> 6;   // 0 = NLL, 1 = Viterbi
    const int tid  = threadIdx.x;

    __shared__ float em_s[Tn*Ln];          // 43008 B
    __shared__ int   lab_s[Tn];            // 2048 B (labels for NLL, attn mask for Viterbi)
    __shared__ float trans_s[Ln*Ln];       // 1764 B
    __shared__ unsigned char hist_s[Tn*Ln];// 10752 B (viterbi backpointers)
    __shared__ int   path_s[Tn];           // 2048 B

    const float* emb = em_g + (size_t)b*Tn*Ln;
    for (int i=tid;i<Tn*Ln;i+=64) em_s[i]=emb[i];
    const int* lsrc = (mode==0) ? (labels + b*Tn) : (amask + b*Tn);
    for (int t=tid;t<Tn;t+=64) lab_s[t]=lsrc[t];
    for (int i=tid;i<Ln*Ln;i+=64) trans_s[i]=trans[i];
    __syncthreads();

    const int  j   = tid;
    const bool act = (j < Ln);
    const int  jc  = act ? j : 0;

    if (mode == 0) {
        // ---- forward algorithm (logZ) in scaled-prob domain ----
        float Ec[Ln];
        #pragma unroll
        for (int i=0;i<Ln;++i) Ec[i] = __expf(trans_s[i*Ln+jc]);
        float alpha = act ? (st[j] + em_s[j]) : -1e30f;
        for (int t=1;t<Tn;++t){
            if (lab_s[t] != -100){                       // uniform branch
                float m = alpha;
                #pragma unroll
                for (int off=32; off>=1; off>>=1) m = fmaxf(m, __shfl_xor(m, off, 64));
                float a = __expf(alpha - m);             // inactive lanes -> 0
                float s0=0.f,s1=0.f,s2=0.f;
                #pragma unroll
                for (int i=0;i<Ln;++i){
                    float ai = __shfl(a, i, 64);
                    float f  = ai * Ec[i];
                    if      (i%3==0) s0+=f;
                    else if (i%3==1) s1+=f;
                    else             s2+=f;
                }
                float nxt = m + __logf((s0+s1)+s2) + em_s[t*Ln+jc];
                alpha = act ? nxt : -1e30f;
            }
        }
        float val = act ? (alpha + et[j]) : -1e30f;
        float mm = val;
        #pragma unroll
        for (int off=32; off>=1; off>>=1) mm = fmaxf(mm, __shfl_xor(mm, off, 64));
        float sse = __expf(val - mm);
        #pragma unroll
        for (int off=32; off>=1; off>>=1) sse += __shfl_xor(sse, off, 64);
        float logZ = mm + __logf(sse);

        // ---- gold score (lane-parallel gather sum) ----
        float part = 0.f;
        for (int t=1+tid; t<Tn; t+=64){
            int lab = lab_s[t];
            if (lab != -100){
                int pv = lab_s[t-1]; if (pv<0) pv=0;
                part += trans_s[pv*Ln+lab] + em_s[t*Ln+lab];
            }
        }
        int cnt = 0;
        for (int t=tid;t<Tn;t+=64) cnt += (t==0 || lab_s[t]!=-100) ? 1 : 0;
        #pragma unroll
        for (int off=32; off>=1; off>>=1){
            part += __shfl_xor(part, off, 64);
            cnt  += __shfl_xor(cnt,  off, 64);
        }
        if (tid==0){
            int l0 = lab_s[0]; int tag0 = l0<0?0:l0;
            float score = st[tag0] + em_s[tag0] + part;
            int li = cnt-1;
            int ll = lab_s[li]; int ltag = ll<0?0:ll;
            score += et[ltag];
            ws_out[b] = score - logZ;
        }
    } else {
        // ---- Viterbi forward ----
        float trc[Ln];
        #pragma unroll
        for (int i=0;i<Ln;++i) trc[i] = trans_s[i*Ln+jc];
        float sc = act ? (st[j] + em_s[j]) : -1e30f;
        for (int t=1;t<Tn;++t){
            if (lab_s[t]){                               // attention mask, uniform
                float best = -3e30f; int bi = 0;
                #pragma unroll
                for (int i=0;i<Ln;++i){
                    float v = __shfl(sc, i, 64) + trc[i];
                    if (v > best){ best=v; bi=i; }       // strict > => first max
                }
                if (act) hist_s[t*Ln+j] = (unsigned char)bi;
                sc = act ? (best + em_s[t*Ln+jc]) : -1e30f;
            } else {
                if (act) hist_s[t*Ln+j] = (unsigned char)j;  // identity backpointer
            }
        }
        // argmax over final scores (first max on ties)
        float val = act ? (sc + et[j]) : -1e30f;
        int   idx = act ? j : 1000;
        #pragma unroll
        for (int off=32; off>=1; off>>=1){
            float ov = __shfl_xor(val, off, 64);
            int   oi = __shfl_xor(idx, off, 64);
            if (ov > val || (ov==val && oi<idx)){ val=ov; idx=oi; }
        }
        __syncthreads();
        if (tid==0){
            int tag = idx;
            path_s[Tn-1]=tag;
            for (int t=Tn-2;t>=0;--t){ tag = hist_s[(t+1)*Ln+tag]; path_s[t]=tag; }
        }
        __syncthreads();
        // one-hot * mask
        float* lg = logits + (size_t)b*Tn*Ln;
        for (int id2=tid; id2<Tn*Ln; id2+=64){
            int t = id2/Ln; int jj = id2 - t*Ln;
            lg[id2] = (lab_s[t] && path_s[t]==jj) ? 1.0f : 0.0f;
        }
    }
}

// ---------------- finalize: nll = -mean(score - logZ) ----------------
__global__ __launch_bounds__(64) void fin_kernel(const float* __restrict__ ws_in,
                                                 float* __restrict__ out0)
{
    float v = ws_in[threadIdx.x];
    #pragma unroll
    for (int off=32; off>=1; off>>=1) v += __shfl_xor(v, off, 64);
    if (threadIdx.x==0) out0[0] = -(v * (1.0f/64.0f));
}

extern "C" void kernel_launch(void* const* d_in, const int* in_sizes, int n_in,
                              void* d_out, int out_size, void* d_ws, size_t ws_size,
                              hipStream_t stream)
{
    (void)in_sizes; (void)n_in; (void)out_size; (void)ws_size;
    const float* hidden = (const float*)d_in[0];
    const float* W      = (const float*)d_in[1];
    const float* bias   = (const float*)d_in[2];
    const float* st     = (const float*)d_in[3];
    const float* et     = (const float*)d_in[4];
    const float* trans  = (const float*)d_in[5];
    const int*   labels = (const int*)d_in[6];
    const int*   amask  = (const int*)d_in[7];

    float* out    = (float*)d_out;
    float* nll    = out;
    float* logits = out + 1;
    float* em     = out + 1 + EM_ELEMS;
    float* ws     = (float*)d_ws;

    emis_kernel<<<dim3(Bn*Tn/128), dim3(128), 0, stream>>>(hidden, W, bias, em);
    crf_kernel<<<dim3(2*Bn), dim3(64), 0, stream>>>(em, labels, amask, st, et, trans, ws, logits);
    fin_kernel<<<dim3(1), dim3(64), 0, stream>>>(ws, nll);
}

// Round 2
// 289.364 us; speedup vs baseline: 1.0768x; 1.0768x over previous
//
#include <hip/hip_runtime.h>

#define Bn 64
#define Tn 512
#define Hn 768
#define Ln 21
#define EM_ELEMS (Bn*Tn*Ln)

__device__ __forceinline__ float rl(float x, int i){
    return __int_as_float(__builtin_amdgcn_readlane(__float_as_int(x), i));
}

// ---------------- emissions = hidden @ W + b ----------------
__global__ __launch_bounds__(128) void emis_kernel(
    const float* __restrict__ hidden, const float* __restrict__ W,
    const float* __restrict__ bias, float* __restrict__ em)
{
    __shared__ float Wl[Hn*Ln];
    for (int i = threadIdx.x; i < Hn*Ln; i += 128) Wl[i] = W[i];
    __syncthreads();
    int row = blockIdx.x*128 + threadIdx.x;           // 0 .. B*T-1
    const float4* h4 = (const float4*)(hidden + (size_t)row*Hn);
    float acc[Ln];
    #pragma unroll
    for (int j=0;j<Ln;++j) acc[j]=bias[j];
    #pragma unroll 4
    for (int k4=0;k4<Hn/4;++k4){
        float4 h = h4[k4];
        const float* hv = &h.x;
        #pragma unroll
        for (int c=0;c<4;++c){
            float x = hv[c];
            const float* wr = &Wl[(k4*4+c)*Ln];
            #pragma unroll
            for (int j=0;j<Ln;++j) acc[j] = fmaf(x, wr[j], acc[j]);
        }
    }
    float* o = em + (size_t)row*Ln;
    #pragma unroll
    for (int j=0;j<Ln;++j) o[j]=acc[j];
}

// ---------------- CRF: blocks 0..63 = NLL, 64..127 = Viterbi ----------------
__global__ __launch_bounds__(64) void crf_kernel(
    const float* __restrict__ em_g, const int* __restrict__ labels,
    const int* __restrict__ amask, const float* __restrict__ st,
    const float* __restrict__ et, const float* __restrict__ trans,
    float* __restrict__ ws_out, float* __restrict__ logits)
{
    const int b    = blockIdx.x & (Bn-1);
    const int mode = blockIdx.x >> 6;   // 0 = NLL, 1 = Viterbi
    const int tid  = threadIdx.x;

    __shared__ float em_s[Tn*Ln];           // 43008 B
    __shared__ int   lab_s[Tn];             // 2048 B
    __shared__ float trans_s[Ln*Ln];        // 1764 B
    __shared__ unsigned char hist_s[Tn*Ln]; // 10752 B
    __shared__ int   path_s[Tn];            // 2048 B
    __shared__ unsigned char comp_s[64*Ln]; // 1344 B
    __shared__ unsigned char ent_s[64];     // 64 B

    const float* emb = em_g + (size_t)b*Tn*Ln;
    for (int i=tid;i<Tn*Ln;i+=64) em_s[i]=emb[i];
    const int* lsrc = (mode==0) ? (labels + b*Tn) : (amask + b*Tn);
    for (int t=tid;t<Tn;t+=64) lab_s[t]=lsrc[t];
    for (int i=tid;i<Ln*Ln;i+=64) trans_s[i]=trans[i];
    __syncthreads();

    const int  j   = tid;
    const bool act = (j < Ln);
    const int  jc  = act ? j : 0;

    if (mode == 0) {
        // ---- gold score first (needs RAW emissions) ----
        float part = 0.f;
        for (int t=1+tid; t<Tn; t+=64){
            int lab = lab_s[t];
            if (lab != -100){
                int pv = lab_s[t-1]; if (pv<0) pv=0;
                part += trans_s[pv*Ln+lab] + em_s[t*Ln+lab];
            }
        }
        int cnt = 0;
        for (int t=tid;t<Tn;t+=64) cnt += (t==0 || lab_s[t]!=-100) ? 1 : 0;
        #pragma unroll
        for (int off=32; off>=1; off>>=1){
            part += __shfl_xor(part, off, 64);
            cnt  += __shfl_xor(cnt,  off, 64);
        }
        float score = 0.f;
        if (tid==0){
            int l0 = lab_s[0]; int tag0 = l0<0?0:l0;
            score = st[tag0] + em_s[tag0] + part;
            int li = cnt-1;
            int ll = lab_s[li]; int ltag = ll<0?0:ll;
            score += et[ltag];
        }
        __syncthreads();
        // ---- transform em_s -> exp(em_s) in place ----
        for (int i=tid;i<Tn*Ln;i+=64) em_s[i] = __expf(em_s[i]);
        __syncthreads();

        // ---- forward algorithm, scaled-prob domain ----
        float Ec[Ln];
        #pragma unroll
        for (int i=0;i<Ln;++i) Ec[i] = __expf(trans_s[i*Ln+jc]);
        float p = act ? (__expf(st[j]) * em_s[jc]) : 0.f;
        float M = 0.f;
        float emt_pref = em_s[Ln + jc];
        int   lab_pref = lab_s[1];
        for (int t=1;t<Tn;++t){
            float emt = emt_pref;
            int   labt = lab_pref;
            int tn = (t < Tn-1) ? (t+1) : (Tn-1);
            emt_pref = em_s[tn*Ln + jc];
            lab_pref = lab_s[tn];
            if (labt != -100){
                float s0=0.f,s1=0.f,s2=0.f;
                #pragma unroll
                for (int i=0;i<Ln;++i){
                    float pi = rl(p, i);
                    if      (i%3==0) s0 = fmaf(pi, Ec[i], s0);
                    else if (i%3==1) s1 = fmaf(pi, Ec[i], s1);
                    else             s2 = fmaf(pi, Ec[i], s2);
                }
                p = ((s0+s1)+s2) * emt;
            }
            if ((t & 7) == 0){
                float p0 = rl(p, 0);
                int e; frexpf(p0, &e);
                p = ldexpf(p, -e);
                M += (float)e * 0.6931471805599453f;
            }
        }
        float val = act ? (p * __expf(et[j])) : 0.f;
        #pragma unroll
        for (int off=32; off>=1; off>>=1) val += __shfl_xor(val, off, 64);
        float logZ = M + __logf(val);
        if (tid==0) ws_out[b] = score - logZ;
    } else {
        // ---- Viterbi forward ----
        float trc[Ln];
        #pragma unroll
        for (int i=0;i<Ln;++i) trc[i] = trans_s[i*Ln+jc];
        float sc = act ? (st[j] + em_s[jc]) : -1e30f;
        float emt_pref = em_s[Ln + jc];
        int   lab_pref = lab_s[1];
        for (int t=1;t<Tn;++t){
            float emt = emt_pref;
            int   labt = lab_pref;
            int tn = (t < Tn-1) ? (t+1) : (Tn-1);
            emt_pref = em_s[tn*Ln + jc];
            lab_pref = lab_s[tn];
            if (labt){
                float v[Ln];
                #pragma unroll
                for (int i=0;i<Ln;++i) v[i] = rl(sc, i) + trc[i];
                float a0 = fmaxf(fmaxf(v[0],v[1]),v[2]);
                float a1 = fmaxf(fmaxf(v[3],v[4]),v[5]);
                float a2 = fmaxf(fmaxf(v[6],v[7]),v[8]);
                float a3 = fmaxf(fmaxf(v[9],v[10]),v[11]);
                float a4 = fmaxf(fmaxf(v[12],v[13]),v[14]);
                float a5 = fmaxf(fmaxf(v[15],v[16]),v[17]);
                float a6 = fmaxf(fmaxf(v[18],v[19]),v[20]);
                float b0 = fmaxf(fmaxf(a0,a1),a2);
                float b1 = fmaxf(fmaxf(a3,a4),a5);
                float best = fmaxf(fmaxf(b0,b1),a6);
                unsigned bm = 0u;
                #pragma unroll
                for (int i=0;i<Ln;++i) bm |= (v[i]==best) ? (1u<<i) : 0u;
                int bi = __ffs(bm) - 1;
                if (act) hist_s[t*Ln+j] = (unsigned char)bi;
                sc = best + emt;
            } else {
                if (act) hist_s[t*Ln+j] = (unsigned char)j;
            }
        }
        // final argmax over lanes (first max on ties)
        float val = act ? (sc + et[j]) : -1e30f;
        int   idx = act ? j : 1000;
        #pragma unroll
        for (int off=32; off>=1; off>>=1){
            float ov = __shfl_xor(val, off, 64);
            int   oi = __shfl_xor(idx, off, 64);
            if (ov > val || (ov==val && oi<idx)){ val=ov; idx=oi; }
        }
        __syncthreads();   // hist complete

        // ---- parallel backtrack: chunk composition ----
        unsigned char cur[Ln];
        #pragma unroll
        for (int q=0;q<Ln;++q) cur[q] = (unsigned char)q;
        #pragma unroll
        for (int k=8;k>=1;--k){
            int ta = 8*tid + k;
            if (ta < Tn){
                const unsigned char* hr = &hist_s[ta*Ln];
                #pragma unroll
                for (int q=0;q<Ln;++q) cur[q] = hr[cur[q]];
            }
        }
        #pragma unroll
        for (int q=0;q<Ln;++q) comp_s[tid*Ln+q] = cur[q];
        __syncthreads();
        if (tid==0){
            int cg = idx;  // last tag
            for (int l=63;l>=0;--l){ ent_s[l]=(unsigned char)cg; cg = comp_s[l*Ln+cg]; }
        }
        __syncthreads();
        int s = ent_s[tid];
        if (tid==63) path_s[Tn-1] = s;
        #pragma unroll
        for (int k=8;k>=1;--k){
            int ta = 8*tid + k;
            if (ta < Tn){ s = hist_s[ta*Ln+s]; path_s[ta-1] = s; }
        }
        __syncthreads();

        // one-hot * mask
        float* lg = logits + (size_t)b*Tn*Ln;
        for (int id2=tid; id2<Tn*Ln; id2+=64){
            int t = id2/Ln; int jj = id2 - t*Ln;
            lg[id2] = (lab_s[t] && path_s[t]==jj) ? 1.0f : 0.0f;
        }
    }
}

// ---------------- finalize: nll = -mean(score - logZ) ----------------
__global__ __launch_bounds__(64) void fin_kernel(const float* __restrict__ ws_in,
                                                 float* __restrict__ out0)
{
    float v = ws_in[threadIdx.x];
    #pragma unroll
    for (int off=32; off>=1; off>>=1) v += __shfl_xor(v, off, 64);
    if (threadIdx.x==0) out0[0] = -(v * (1.0f/64.0f));
}

extern "C" void kernel_launch(void* const* d_in, const int* in_sizes, int n_in,
                              void* d_out, int out_size, void* d_ws, size_t ws_size,
                              hipStream_t stream)
{
    (void)in_sizes; (void)n_in; (void)out_size; (void)ws_size;
    const float* hidden = (const float*)d_in[0];
    const float* W      = (const float*)d_in[1];
    const float* bias   = (const float*)d_in[2];
    const float* st     = (const float*)d_in[3];
    const float* et     = (const float*)d_in[4];
    const float* trans  = (const float*)d_in[5];
    const int*   labels = (const int*)d_in[6];
    const int*   amask  = (const int*)d_in[7];

    float* out    = (float*)d_out;
    float* nll    = out;
    float* logits = out + 1;
    float* em     = out + 1 + EM_ELEMS;
    float* ws     = (float*)d_ws;

    emis_kernel<<<dim3(Bn*Tn/128), dim3(128), 0, stream>>>(hidden, W, bias, em);
    crf_kernel<<<dim3(2*Bn), dim3(64), 0, stream>>>(em, labels, amask, st, et, trans, ws, logits);
    fin_kernel<<<dim3(1), dim3(64), 0, stream>>>(ws, nll);
}

// Round 3
// 227.690 us; speedup vs baseline: 1.3685x; 1.2709x over previous
//
#include <hip/hip_runtime.h>

#define Bn 64
#define Tn 512
#define Hn 768
#define Ln 21
#define EM_ELEMS (Bn*Tn*Ln)

// ws float offsets (total 803008 floats = 3.22 MB)
#define A_OFF    0
#define A_STRIDE 24
#define DUMP_OFF 786432
#define LZ_OFF   802816
#define TAG_OFF  802880
#define DIFF_OFF 802944

__device__ __forceinline__ float rl(float x, int i){
    return __int_as_float(__builtin_amdgcn_readlane(__float_as_int(x), i));
}

// ---------------- emissions = hidden @ W + b (no LDS: W via readlane) ----------------
__global__ __launch_bounds__(128) void emis_kernel(
    const float* __restrict__ hidden, const float* __restrict__ W,
    const float* __restrict__ bias, float* __restrict__ em)
{
    const int row  = blockIdx.x*128 + threadIdx.x;   // 0..B*T-1
    const int lane = threadIdx.x & 63;
    const int wb   = 64 + (lane < 20 ? lane : 19);   // clamp to stay in-bounds
    const float4* h4 = (const float4*)(hidden + (size_t)row*Hn);
    float acc[Ln];
    #pragma unroll
    for (int j=0;j<Ln;++j) acc[j] = bias[j];
    float4 hcur = h4[0];
    float Wa = W[lane];
    float Wb = W[wb];
    for (int t=0;t<192;++t){
        float4 hnex = hcur; float Wan = Wa, Wbn = Wb;
        if (t < 191){
            hnex = h4[t+1];
            Wan = W[(t+1)*84 + lane];
            Wbn = W[(t+1)*84 + wb];
        }
        const float* hv = &hcur.x;
        #pragma unroll
        for (int c=0;c<4;++c){
            float x = hv[c];
            #pragma unroll
            for (int j=0;j<Ln;++j){
                const int idx = c*Ln+j;
                float wv = (idx < 64) ? rl(Wa, idx) : rl(Wb, idx-64);
                acc[j] = fmaf(x, wv, acc[j]);
            }
        }
        hcur = hnex; Wa = Wan; Wb = Wbn;
    }
    float* o = em + (size_t)row*Ln;
    #pragma unroll
    for (int j=0;j<Ln;++j) o[j] = acc[j];
}

// ---------------- scans: blocks 0..63 viterbi fwd (store alpha), 64..127 NLL ----------------
__global__ __launch_bounds__(64) void scan_kernel(
    const float* __restrict__ em, const int* __restrict__ labels,
    const int* __restrict__ amask, const float* __restrict__ st,
    const float* __restrict__ et, const float* __restrict__ trans,
    float* __restrict__ ws)
{
    const int b    = blockIdx.x & (Bn-1);
    const int mode = blockIdx.x >> 6;
    const int j    = threadIdx.x;
    const bool act = (j < Ln);
    const int  jc  = act ? j : 0;
    const float* emb = em + (size_t)b*Tn*Ln;

    if (mode == 0){
        // ---- Viterbi forward: only the value recurrence; alpha streamed to ws ----
        float trc[Ln];
        #pragma unroll
        for (int i=0;i<Ln;++i) trc[i] = trans[i*Ln + jc];
        const int* mk = amask + b*Tn;
        float sc = act ? (st[j] + emb[j]) : -1e30f;
        float* sp = act ? (ws + A_OFF + (size_t)b*Tn*A_STRIDE + j)
                        : (ws + DUMP_OFF + j);
        *sp = sc; sp += A_STRIDE;
        float e1 = emb[Ln + jc];    int m1 = mk[1];
        float e2 = emb[2*Ln + jc];  int m2 = mk[2];
        for (int t=1;t<Tn;++t){
            float ec = e1; int mc = m1;
            e1 = e2; m1 = m2;
            int tn = (t+2 < Tn) ? (t+2) : (Tn-1);
            e2 = emb[tn*Ln + jc]; m2 = mk[tn];
            float v[Ln];
            #pragma unroll
            for (int i=0;i<Ln;++i) v[i] = rl(sc,i) + trc[i];
            float a0 = fmaxf(fmaxf(v[0],v[1]),v[2]);
            float a1 = fmaxf(fmaxf(v[3],v[4]),v[5]);
            float a2 = fmaxf(fmaxf(v[6],v[7]),v[8]);
            float a3 = fmaxf(fmaxf(v[9],v[10]),v[11]);
            float a4 = fmaxf(fmaxf(v[12],v[13]),v[14]);
            float a5 = fmaxf(fmaxf(v[15],v[16]),v[17]);
            float a6 = fmaxf(fmaxf(v[18],v[19]),v[20]);
            float b0 = fmaxf(fmaxf(a0,a1),a2);
            float b1 = fmaxf(fmaxf(a3,a4),a5);
            float best = fmaxf(fmaxf(b0,b1),a6);
            float scn = best + ec;
            sc = mc ? scn : sc;
            *sp = sc; sp += A_STRIDE;
        }
        float val = act ? (sc + et[j]) : -1e30f;
        int   idx = act ? j : 1000;
        #pragma unroll
        for (int off=32; off>=1; off>>=1){
            float ov = __shfl_xor(val, off, 64);
            int   oi = __shfl_xor(idx, off, 64);
            if (ov > val || (ov==val && oi<idx)){ val=ov; idx=oi; }
        }
        if (j==0) ((int*)(ws+TAG_OFF))[b] = idx;
    } else {
        // ---- NLL forward in scaled-prob domain ----
        float Ec[Ln];
        #pragma unroll
        for (int i=0;i<Ln;++i) Ec[i] = __expf(trans[i*Ln + jc]);
        const int* lb = labels + b*Tn;
        float p = act ? __expf(st[j] + emb[j]) : 0.f;
        float M = 0.f;
        float e1 = emb[Ln + jc];    int l1 = lb[1];
        float e2 = emb[2*Ln + jc];  int l2 = lb[2];
        for (int t=1;t<Tn;++t){
            float ec = e1; int lc = l1;
            e1 = e2; l1 = l2;
            int tn = (t+2 < Tn) ? (t+2) : (Tn-1);
            e2 = emb[tn*Ln + jc]; l2 = lb[tn];
            float pe = __expf(ec);
            float s0=0.f,s1=0.f,s2=0.f;
            #pragma unroll
            for (int i=0;i<Ln;++i){
                float pi = rl(p,i);
                if      (i%3==0) s0 = fmaf(pi, Ec[i], s0);
                else if (i%3==1) s1 = fmaf(pi, Ec[i], s1);
                else             s2 = fmaf(pi, Ec[i], s2);
            }
            float pn = ((s0+s1)+s2) * pe;
            p = (lc != -100) ? pn : p;
            if ((t & 7) == 0){
                float p0 = rl(p,0);
                int e; frexpf(p0, &e);
                p = ldexpf(p, -e);
                M += (float)e * 0.6931471805599453f;
            }
        }
        float val = p * __expf(et[jc]);   // p==0 for inactive lanes
        #pragma unroll
        for (int off=32; off>=1; off>>=1) val += __shfl_xor(val, off, 64);
        if (j==0) (ws+LZ_OFF)[b] = M + __logf(val);
    }
}

// ---------------- post: blocks 0..63 bp-recompute+backtrack+logits; 64..127 gold score ----------------
__global__ __launch_bounds__(512) void post_kernel(
    const float* __restrict__ em, const int* __restrict__ labels,
    const int* __restrict__ amask, const float* __restrict__ st,
    const float* __restrict__ et, const float* __restrict__ trans,
    float* __restrict__ ws, float* __restrict__ logits)
{
    const int b    = blockIdx.x & (Bn-1);
    const int mode = blockIdx.x >> 6;
    const int tid  = threadIdx.x;

    if (mode == 0){
        __shared__ unsigned char hist_s[Tn*Ln];
        __shared__ int lab_s[Tn];
        __shared__ int path_s[Tn];
        __shared__ unsigned char comp_s[64*Ln];
        __shared__ unsigned char ent_s[64];
        lab_s[tid] = amask[b*Tn + tid];
        const int w = tid >> 6, lane = tid & 63;
        const bool act = lane < Ln;
        const int jc = act ? lane : 0;
        float trc[Ln];
        #pragma unroll
        for (int i=0;i<Ln;++i) trc[i] = trans[i*Ln + jc];
        __syncthreads();
        const float* wsA = ws + A_OFF + (size_t)b*Tn*A_STRIDE;
        for (int t = 1+w; t < Tn; t += 8){
            const float4* ar = (const float4*)(wsA + (size_t)(t-1)*A_STRIDE);
            float4 A0=ar[0],A1=ar[1],A2=ar[2],A3=ar[3],A4=ar[4],A5=ar[5];
            float a[24] = {A0.x,A0.y,A0.z,A0.w, A1.x,A1.y,A1.z,A1.w,
                           A2.x,A2.y,A2.z,A2.w, A3.x,A3.y,A3.z,A3.w,
                           A4.x,A4.y,A4.z,A4.w, A5.x,A5.y,A5.z,A5.w};
            int bp = lane;
            if (lab_s[t]){
                float v[Ln];
                #pragma unroll
                for (int i=0;i<Ln;++i) v[i] = a[i] + trc[i];
                float a0 = fmaxf(fmaxf(v[0],v[1]),v[2]);
                float a1 = fmaxf(fmaxf(v[3],v[4]),v[5]);
                float a2 = fmaxf(fmaxf(v[6],v[7]),v[8]);
                float a3 = fmaxf(fmaxf(v[9],v[10]),v[11]);
                float a4 = fmaxf(fmaxf(v[12],v[13]),v[14]);
                float a5 = fmaxf(fmaxf(v[15],v[16]),v[17]);
                float a6 = fmaxf(fmaxf(v[18],v[19]),v[20]);
                float b0 = fmaxf(fmaxf(a0,a1),a2);
                float b1 = fmaxf(fmaxf(a3,a4),a5);
                float best = fmaxf(fmaxf(b0,b1),a6);
                unsigned bm = 0u;
                #pragma unroll
                for (int i=0;i<Ln;++i) bm |= (v[i]==best) ? (1u<<i) : 0u;
                bp = __ffs(bm) - 1;
            }
            if (act) hist_s[t*Ln + lane] = (unsigned char)bp;
        }
        __syncthreads();
        if (tid < 64){
            unsigned char cur[Ln];
            #pragma unroll
            for (int q=0;q<Ln;++q) cur[q] = (unsigned char)q;
            #pragma unroll
            for (int k=8;k>=1;--k){
                int ta = 8*tid + k;
                if (ta < Tn){
                    const unsigned char* hr = &hist_s[ta*Ln];
                    #pragma unroll
                    for (int q=0;q<Ln;++q) cur[q] = hr[cur[q]];
                }
            }
            #pragma unroll
            for (int q=0;q<Ln;++q) comp_s[tid*Ln+q] = cur[q];
        }
        __syncthreads();
        if (tid==0){
            int cg = ((const int*)(ws+TAG_OFF))[b];
            for (int l=63;l>=0;--l){ ent_s[l]=(unsigned char)cg; cg = comp_s[l*Ln+cg]; }
        }
        __syncthreads();
        if (tid < 64){
            int s = ent_s[tid];
            if (tid==63) path_s[Tn-1] = s;
            #pragma unroll
            for (int k=8;k>=1;--k){
                int ta = 8*tid + k;
                if (ta < Tn){ s = hist_s[ta*Ln+s]; path_s[ta-1] = s; }
            }
        }
        __syncthreads();
        float* lg = logits + (size_t)b*Tn*Ln;
        for (int id2=tid; id2<Tn*Ln; id2+=512){
            int t = id2/Ln; int jj = id2 - t*Ln;
            lg[id2] = (lab_s[t] && path_s[t]==jj) ? 1.0f : 0.0f;
        }
    } else {
        __shared__ float red_s[8];
        __shared__ int  redc_s[8];
        const int* lb = labels + b*Tn;
        int labt = lb[tid];
        float term = 0.f;
        int c = (tid==0 || labt != -100) ? 1 : 0;
        if (tid>=1 && labt != -100){
            int lp = lb[tid-1]; if (lp<0) lp=0;
            term = trans[lp*Ln+labt] + em[((size_t)b*Tn+tid)*Ln + labt];
        }
        #pragma unroll
        for (int off=32; off>=1; off>>=1){
            term += __shfl_xor(term, off, 64);
            c    += __shfl_xor(c,    off, 64);
        }
        int w = tid>>6;
        if ((tid&63)==0){ red_s[w]=term; redc_s[w]=c; }
        __syncthreads();
        if (tid==0){
            float sum=0.f; int cnt=0;
            #pragma unroll
            for (int q=0;q<8;++q){ sum+=red_s[q]; cnt+=redc_s[q]; }
            int l0 = lb[0]; int tag0 = l0<0?0:l0;
            float score = st[tag0] + em[(size_t)b*Tn*Ln + tag0] + sum;
            int li = cnt-1; int ll = lb[li]; int lt = ll<0?0:ll;
            score += et[lt];
            (ws+DIFF_OFF)[b] = score - (ws+LZ_OFF)[b];
        }
    }
}

// ---------------- finalize: nll = -mean(score - logZ) ----------------
__global__ __launch_bounds__(64) void fin_kernel(const float* __restrict__ ws,
                                                 float* __restrict__ out0)
{
    float v = (ws+DIFF_OFF)[threadIdx.x];
    #pragma unroll
    for (int off=32; off>=1; off>>=1) v += __shfl_xor(v, off, 64);
    if (threadIdx.x==0) out0[0] = -(v * (1.0f/64.0f));
}

extern "C" void kernel_launch(void* const* d_in, const int* in_sizes, int n_in,
                              void* d_out, int out_size, void* d_ws, size_t ws_size,
                              hipStream_t stream)
{
    (void)in_sizes; (void)n_in; (void)out_size; (void)ws_size;
    const float* hidden = (const float*)d_in[0];
    const float* W      = (const float*)d_in[1];
    const float* bias   = (const float*)d_in[2];
    const float* st     = (const float*)d_in[3];
    const float* et     = (const float*)d_in[4];
    const float* trans  = (const float*)d_in[5];
    const int*   labels = (const int*)d_in[6];
    const int*   amask  = (const int*)d_in[7];

    float* out    = (float*)d_out;
    float* nll    = out;
    float* logits = out + 1;
    float* em     = out + 1 + EM_ELEMS;
    float* ws     = (float*)d_ws;

    emis_kernel<<<dim3(Bn*Tn/128), dim3(128), 0, stream>>>(hidden, W, bias, em);
    scan_kernel<<<dim3(2*Bn), dim3(64), 0, stream>>>(em, labels, amask, st, et, trans, ws);
    post_kernel<<<dim3(2*Bn), dim3(512), 0, stream>>>(em, labels, amask, st, et, trans, ws, logits);
    fin_kernel<<<dim3(1), dim3(64), 0, stream>>>(ws, nll);
}

// Round 4
// 190.133 us; speedup vs baseline: 1.6388x; 1.1975x over previous
//
#include <hip/hip_runtime.h>

#define Bn 64
#define Tn 512
#define Hn 768
#define Ln 21
#define EM_ELEMS (Bn*Tn*Ln)

// tiny ws layout (floats) — total 256 floats = 1 KB
#define DUMP_OFF 0
#define LZ_OFF   64
#define TAG_OFF  128
#define DIFF_OFF 192

__device__ __forceinline__ float rl(float x, int i){
    return __int_as_float(__builtin_amdgcn_readlane(__float_as_int(x), i));
}

// ---------------- emissions = hidden @ W + b  (split-K x4, LDS combine) ----------------
// 512 blocks x 256 threads; 64 rows/block; wave w handles k in [w*192, (w+1)*192)
__global__ __launch_bounds__(256) void emis_kernel(
    const float* __restrict__ hidden, const float* __restrict__ W,
    const float* __restrict__ bias, float* __restrict__ em)
{
    __shared__ float part[4][64][22];
    const int lane = threadIdx.x & 63;
    const int w    = threadIdx.x >> 6;
    const int row  = blockIdx.x*64 + lane;
    const int wb   = 64 + (lane < 20 ? lane : 19);
    const float4* h4 = (const float4*)(hidden + (size_t)row*Hn) + w*48;
    const float*  Wp = W + w*(192*Ln);
    float acc[Ln];
    #pragma unroll
    for (int j=0;j<Ln;++j) acc[j]=0.f;
    float4 hcur = h4[0];
    float Wa = Wp[lane], Wb2 = Wp[wb];
    for (int t=0;t<48;++t){
        float4 hn = hcur; float Wan = Wa, Wbn = Wb2;
        if (t<47){ hn = h4[t+1]; Wan = Wp[(t+1)*84+lane]; Wbn = Wp[(t+1)*84+wb]; }
        const float* hv = &hcur.x;
        #pragma unroll
        for (int c=0;c<4;++c){
            float x = hv[c];
            #pragma unroll
            for (int j=0;j<Ln;++j){
                const int idx = c*Ln+j;
                float wv = (idx<64) ? rl(Wa, idx) : rl(Wb2, idx-64);
                acc[j] = fmaf(x, wv, acc[j]);
            }
        }
        hcur=hn; Wa=Wan; Wb2=Wbn;
    }
    #pragma unroll
    for (int j=0;j<Ln;++j) part[w][lane][j] = acc[j];
    __syncthreads();
    float* ob = em + (size_t)blockIdx.x*64*Ln;
    for (int e=threadIdx.x; e<64*Ln; e+=256){
        int r = e/Ln, j = e-r*Ln;
        ob[e] = ((part[0][r][j]+part[1][r][j])+(part[2][r][j]+part[3][r][j])) + bias[j];
    }
}

// ---------------- scans: blocks 0..63 viterbi fwd (alpha -> logits region), 64..127 NLL ----------------
__global__ __launch_bounds__(64) void scan_kernel(
    const float* __restrict__ em, const int* __restrict__ labels,
    const int* __restrict__ amask, const float* __restrict__ st,
    const float* __restrict__ et, const float* __restrict__ trans,
    float* __restrict__ ws, float* __restrict__ alf)
{
    const int b    = blockIdx.x & (Bn-1);
    const int mode = blockIdx.x >> 6;
    const int j    = threadIdx.x;
    const bool act = (j < Ln);
    const int  jc  = act ? j : 0;
    const float* emb = em + (size_t)b*Tn*Ln;

    if (mode == 0){
        // ---- Viterbi forward: value recurrence only; alpha streamed into logits region ----
        float trc[Ln];
        #pragma unroll
        for (int i=0;i<Ln;++i) trc[i] = trans[i*Ln + jc];
        const int* mk = amask + b*Tn;
        float sc = act ? (st[j] + emb[j]) : -1e30f;
        float* sp = act ? (alf + (size_t)b*Tn*Ln + j) : (ws + DUMP_OFF + j);
        const int sstep = act ? Ln : 0;
        *sp = sc; sp += sstep;
        float e1 = emb[Ln + jc];    int m1 = mk[1];
        float e2 = emb[2*Ln + jc];  int m2 = mk[2];
        for (int t=1;t<Tn;++t){
            float ec = e1; int mc = m1;
            e1 = e2; m1 = m2;
            int tn = (t+2 < Tn) ? (t+2) : (Tn-1);
            e2 = emb[tn*Ln + jc]; m2 = mk[tn];
            float v[Ln];
            #pragma unroll
            for (int i=0;i<Ln;++i) v[i] = rl(sc,i) + trc[i];
            float a0 = fmaxf(fmaxf(v[0],v[1]),v[2]);
            float a1 = fmaxf(fmaxf(v[3],v[4]),v[5]);
            float a2 = fmaxf(fmaxf(v[6],v[7]),v[8]);
            float a3 = fmaxf(fmaxf(v[9],v[10]),v[11]);
            float a4 = fmaxf(fmaxf(v[12],v[13]),v[14]);
            float a5 = fmaxf(fmaxf(v[15],v[16]),v[17]);
            float a6 = fmaxf(fmaxf(v[18],v[19]),v[20]);
            float b0 = fmaxf(fmaxf(a0,a1),a2);
            float b1 = fmaxf(fmaxf(a3,a4),a5);
            float best = fmaxf(fmaxf(b0,b1),a6);
            float scn = best + ec;
            sc = mc ? scn : sc;
            *sp = sc; sp += sstep;
        }
        float val = act ? (sc + et[j]) : -1e30f;
        int   idx = act ? j : 1000;
        #pragma unroll
        for (int off=32; off>=1; off>>=1){
            float ov = __shfl_xor(val, off, 64);
            int   oi = __shfl_xor(idx, off, 64);
            if (ov > val || (ov==val && oi<idx)){ val=ov; idx=oi; }
        }
        if (j==0) ((int*)(ws+TAG_OFF))[b] = idx;
    } else {
        // ---- NLL forward in scaled-prob domain ----
        float Ec[Ln];
        #pragma unroll
        for (int i=0;i<Ln;++i) Ec[i] = __expf(trans[i*Ln + jc]);
        const int* lb = labels + b*Tn;
        float p = act ? __expf(st[j] + emb[j]) : 0.f;
        float M = 0.f;
        float e1 = emb[Ln + jc];    int l1 = lb[1];
        float e2 = emb[2*Ln + jc];  int l2 = lb[2];
        for (int t=1;t<Tn;++t){
            float ec = e1; int lc = l1;
            e1 = e2; l1 = l2;
            int tn = (t+2 < Tn) ? (t+2) : (Tn-1);
            e2 = emb[tn*Ln + jc]; l2 = lb[tn];
            float pe = __expf(ec);
            float s0=0.f,s1=0.f,s2=0.f;
            #pragma unroll
            for (int i=0;i<Ln;++i){
                float pi = rl(p,i);
                if      (i%3==0) s0 = fmaf(pi, Ec[i], s0);
                else if (i%3==1) s1 = fmaf(pi, Ec[i], s1);
                else             s2 = fmaf(pi, Ec[i], s2);
            }
            float pn = ((s0+s1)+s2) * pe;
            p = (lc != -100) ? pn : p;
            if ((t & 7) == 0){
                float p0 = rl(p,0);
                int e; frexpf(p0, &e);
                p = ldexpf(p, -e);
                M += (float)e * 0.6931471805599453f;
            }
        }
        float val = act ? (p * __expf(et[j])) : 0.f;   // mask inactive lanes!
        #pragma unroll
        for (int off=32; off>=1; off>>=1) val += __shfl_xor(val, off, 64);
        if (j==0) (ws+LZ_OFF)[b] = M + __logf(val);
    }
}

// ---------------- post: blocks 0..63 bp-recompute+backtrack+logits; 64..127 gold score ----------------
__global__ __launch_bounds__(512) void post_kernel(
    const float* __restrict__ em, const int* __restrict__ labels,
    const int* __restrict__ amask, const float* __restrict__ st,
    const float* __restrict__ et, const float* __restrict__ trans,
    float* __restrict__ ws, float* __restrict__ logits)
{
    const int b    = blockIdx.x & (Bn-1);
    const int mode = blockIdx.x >> 6;
    const int tid  = threadIdx.x;

    if (mode == 0){
        __shared__ unsigned char hist_s[Tn*Ln];
        __shared__ int lab_s[Tn];
        __shared__ int path_s[Tn];
        __shared__ unsigned char comp_s[64*Ln];
        __shared__ unsigned char ent_s[64];
        lab_s[tid] = amask[b*Tn + tid];
        const int w = tid >> 6, lane = tid & 63;
        const bool act = lane < Ln;
        const int jc = act ? lane : 0;
        float trc[Ln];
        #pragma unroll
        for (int i=0;i<Ln;++i) trc[i] = trans[i*Ln + jc];
        __syncthreads();
        const float* alf = logits + (size_t)b*Tn*Ln;   // alpha lives here (written by scan)
        for (int t = 1+w; t < Tn; t += 8){
            const float* ar = alf + (size_t)(t-1)*Ln;
            float a[Ln];
            #pragma unroll
            for (int i=0;i<Ln;++i) a[i] = ar[i];
            int bp = lane;
            if (lab_s[t]){
                float v[Ln];
                #pragma unroll
                for (int i=0;i<Ln;++i) v[i] = a[i] + trc[i];
                float a0 = fmaxf(fmaxf(v[0],v[1]),v[2]);
                float a1 = fmaxf(fmaxf(v[3],v[4]),v[5]);
                float a2 = fmaxf(fmaxf(v[6],v[7]),v[8]);
                float a3 = fmaxf(fmaxf(v[9],v[10]),v[11]);
                float a4 = fmaxf(fmaxf(v[12],v[13]),v[14]);
                float a5 = fmaxf(fmaxf(v[15],v[16]),v[17]);
                float a6 = fmaxf(fmaxf(v[18],v[19]),v[20]);
                float b0 = fmaxf(fmaxf(a0,a1),a2);
                float b1 = fmaxf(fmaxf(a3,a4),a5);
                float best = fmaxf(fmaxf(b0,b1),a6);
                unsigned bm = 0u;
                #pragma unroll
                for (int i=0;i<Ln;++i) bm |= (v[i]==best) ? (1u<<i) : 0u;
                bp = __ffs(bm) - 1;
            }
            if (act) hist_s[t*Ln + lane] = (unsigned char)bp;
        }
        __syncthreads();
        if (tid < 64){
            unsigned char cur[Ln];
            #pragma unroll
            for (int q=0;q<Ln;++q) cur[q] = (unsigned char)q;
            #pragma unroll
            for (int k=8;k>=1;--k){
                int ta = 8*tid + k;
                if (ta < Tn){
                    const unsigned char* hr = &hist_s[ta*Ln];
                    #pragma unroll
                    for (int q=0;q<Ln;++q) cur[q] = hr[cur[q]];
                }
            }
            #pragma unroll
            for (int q=0;q<Ln;++q) comp_s[tid*Ln+q] = cur[q];
        }
        __syncthreads();
        if (tid==0){
            int cg = ((const int*)(ws+TAG_OFF))[b];
            for (int l=63;l>=0;--l){ ent_s[l]=(unsigned char)cg; cg = comp_s[l*Ln+cg]; }
        }
        __syncthreads();
        if (tid < 64){
            int s = ent_s[tid];
            if (tid==63) path_s[Tn-1] = s;
            #pragma unroll
            for (int k=8;k>=1;--k){
                int ta = 8*tid + k;
                if (ta < Tn){ s = hist_s[ta*Ln+s]; path_s[ta-1] = s; }
            }
        }
        __syncthreads();   // all alpha reads done; now overwrite with one-hot
        float* lg = logits + (size_t)b*Tn*Ln;
        for (int id2=tid; id2<Tn*Ln; id2+=512){
            int t = id2/Ln; int jj = id2 - t*Ln;
            lg[id2] = (lab_s[t] && path_s[t]==jj) ? 1.0f : 0.0f;
        }
    } else {
        __shared__ float red_s[8];
        __shared__ int  redc_s[8];
        const int* lb = labels + b*Tn;
        int labt = lb[tid];
        float term = 0.f;
        int c = (tid==0 || labt != -100) ? 1 : 0;
        if (tid>=1 && labt != -100){
            int lp = lb[tid-1]; if (lp<0) lp=0;
            term = trans[lp*Ln+labt] + em[((size_t)b*Tn+tid)*Ln + labt];
        }
        #pragma unroll
        for (int off=32; off>=1; off>>=1){
            term += __shfl_xor(term, off, 64);
            c    += __shfl_xor(c,    off, 64);
        }
        int w = tid>>6;
        if ((tid&63)==0){ red_s[w]=term; redc_s[w]=c; }
        __syncthreads();
        if (tid==0){
            float sum=0.f; int cnt=0;
            #pragma unroll
            for (int q=0;q<8;++q){ sum+=red_s[q]; cnt+=redc_s[q]; }
            int l0 = lb[0]; int tag0 = l0<0?0:l0;
            float score = st[tag0] + em[(size_t)b*Tn*Ln + tag0] + sum;
            int li = cnt-1; int ll = lb[li]; int lt = ll<0?0:ll;
            score += et[lt];
            (ws+DIFF_OFF)[b] = score - (ws+LZ_OFF)[b];
        }
    }
}

// ---------------- finalize: nll = -mean(score - logZ) ----------------
__global__ __launch_bounds__(64) void fin_kernel(const float* __restrict__ ws,
                                                 float* __restrict__ out0)
{
    float v = (ws+DIFF_OFF)[threadIdx.x];
    #pragma unroll
    for (int off=32; off>=1; off>>=1) v += __shfl_xor(v, off, 64);
    if (threadIdx.x==0) out0[0] = -(v * (1.0f/64.0f));
}

extern "C" void kernel_launch(void* const* d_in, const int* in_sizes, int n_in,
                              void* d_out, int out_size, void* d_ws, size_t ws_size,
                              hipStream_t stream)
{
    (void)in_sizes; (void)n_in; (void)out_size; (void)ws_size;
    const float* hidden = (const float*)d_in[0];
    const float* W      = (const float*)d_in[1];
    const float* bias   = (const float*)d_in[2];
    const float* st     = (const float*)d_in[3];
    const float* et     = (const float*)d_in[4];
    const float* trans  = (const float*)d_in[5];
    const int*   labels = (const int*)d_in[6];
    const int*   amask  = (const int*)d_in[7];

    float* out    = (float*)d_out;
    float* nll    = out;
    float* logits = out + 1;
    float* em     = out + 1 + EM_ELEMS;
    float* ws     = (float*)d_ws;

    emis_kernel<<<dim3(Bn*Tn/64), dim3(256), 0, stream>>>(hidden, W, bias, em);
    scan_kernel<<<dim3(2*Bn), dim3(64), 0, stream>>>(em, labels, amask, st, et, trans, ws, logits);
    post_kernel<<<dim3(2*Bn), dim3(512), 0, stream>>>(em, labels, amask, st, et, trans, ws, logits);
    fin_kernel<<<dim3(1), dim3(64), 0, stream>>>(ws, nll);
}